// Round 1
// baseline (514.418 us; speedup 1.0000x reference)
//
#include <hip/hip_runtime.h>
#include <math.h>

// TimeAwareScaledDotProductAttention, fused single kernel.
// B=8, H=4, L=256, D=32, fp32 in/out.
// Grid: one block per (b,h,q) row = B*H*L = 8192 blocks, 256 threads.
// Dominant traffic: time_matrix_K + time_matrix_V = 512 MB streamed once.

#define LDIM 256
#define DDIM 32
#define NEG_BIG (-4294967295.0f)  // matches torch/jax masked_fill value (rounds to -2^32 in fp32)

__global__ __launch_bounds__(256, 4)
void taspda_fused(const float* __restrict__ Q,
                  const float* __restrict__ K,
                  const float* __restrict__ V,
                  const float* __restrict__ tmK,
                  const float* __restrict__ tmV,
                  const float* __restrict__ attn_mask,
                  const unsigned char* __restrict__ padding_mask,
                  float* __restrict__ x_out,
                  float* __restrict__ attn_out)
{
    const int bid = blockIdx.x;          // bid = (b*H + h)*L + q
    const int q   = bid & (LDIM - 1);
    const int bh  = bid >> 8;            // b*H + h
    const int b   = bh >> 2;             // H = 4
    const int t   = threadIdx.x;
    const int kk  = t >> 3;              // k-group base: k = kk + 32*i
    const int d4  = t & 7;               // which float4 of the 32-float d-dim

    __shared__ float  qlds[DDIM];
    __shared__ float  els[LDIM];         // energy row, then attn row
    __shared__ float  red[8];            // cross-wave reduce scratch (max:0..3, sum:4..7)
    __shared__ float4 xred[256];         // output reduction

    // ---- load Q row (32 floats) into LDS ----
    if (t < DDIM) qlds[t] = Q[(size_t)bid * DDIM + t];
    __syncthreads();
    const float4 q4 = *(const float4*)&qlds[d4 * 4];

    const float4* tmKrow = (const float4*)(tmK + (size_t)bid * LDIM * DDIM);
    const float4* Krow   = (const float4*)(K   + (size_t)bh  * LDIM * DDIM);

    // ---- phase 1: energy[k] = Q . (K[k] + tmK[q,k]) ----
    // Per iteration i the block touches float4 indices [256*i, 256*(i+1)) of the
    // 2048-float4 row: fully coalesced (1 KiB per wave instruction).
    #pragma unroll
    for (int i = 0; i < 8; ++i) {
        const int k = kk + 32 * i;
        const float4 a = tmKrow[k * 8 + d4];
        const float4 c = Krow[k * 8 + d4];
        float s = q4.x * (a.x + c.x) + q4.y * (a.y + c.y)
                + q4.z * (a.z + c.z) + q4.w * (a.w + c.w);
        // reduce across the 8 lanes sharing this k (d4 = 0..7, consecutive lanes)
        s += __shfl_xor(s, 1);
        s += __shfl_xor(s, 2);
        s += __shfl_xor(s, 4);
        if (d4 == 0) els[k] = s;
    }
    __syncthreads();

    // ---- softmax over k (thread t owns k = t) ----
    const float inv_scale = 0.17677669529663687f;   // 1/sqrt(32)
    float e = els[t] * inv_scale + attn_mask[q * LDIM + t];
    if (padding_mask[b * LDIM + t]) e = NEG_BIG;

    // block max (wave shuffle then 4-wave LDS combine)
    float m = e;
    #pragma unroll
    for (int o = 32; o >= 1; o >>= 1) m = fmaxf(m, __shfl_xor(m, o));
    const int wid = t >> 6;
    if ((t & 63) == 0) red[wid] = m;
    __syncthreads();
    m = fmaxf(fmaxf(red[0], red[1]), fmaxf(red[2], red[3]));

    const float p = expf(e - m);
    float s = p;
    #pragma unroll
    for (int o = 32; o >= 1; o >>= 1) s += __shfl_xor(s, o);
    if ((t & 63) == 0) red[4 + wid] = s;
    __syncthreads();
    s = red[4] + red[5] + red[6] + red[7];
    const float attnv = p / s;

    attn_out[(size_t)bid * LDIM + t] = attnv;   // coalesced row write
    els[t] = attnv;                             // safe: all els reads were before the barriers above
    __syncthreads();

    // ---- phase 2: x[d] = sum_k attn[k] * (V[k,d] + tmV[q,k,d]) ----
    const float4* tmVrow = (const float4*)(tmV + (size_t)bid * LDIM * DDIM);
    const float4* Vrow   = (const float4*)(V   + (size_t)bh  * LDIM * DDIM);
    float4 acc = make_float4(0.f, 0.f, 0.f, 0.f);
    #pragma unroll
    for (int i = 0; i < 8; ++i) {
        const int k = kk + 32 * i;
        const float  a  = els[k];          // broadcast within 8-lane group
        const float4 v  = Vrow[k * 8 + d4];
        const float4 tv = tmVrow[k * 8 + d4];
        acc.x += a * (v.x + tv.x);
        acc.y += a * (v.y + tv.y);
        acc.z += a * (v.z + tv.z);
        acc.w += a * (v.w + tv.w);
    }
    // reduce acc over kk (threads with equal d4, stride 8) via LDS tree
    xred[t] = acc;
    __syncthreads();
    #pragma unroll
    for (int o = 128; o >= 8; o >>= 1) {
        if (t < o) {
            float4 other = xred[t + o];
            float4 mine  = xred[t];
            mine.x += other.x; mine.y += other.y;
            mine.z += other.z; mine.w += other.w;
            xred[t] = mine;
        }
        __syncthreads();
    }
    if (t < 8) {
        ((float4*)(x_out + (size_t)bid * DDIM))[t] = xred[t];
    }
}

extern "C" void kernel_launch(void* const* d_in, const int* in_sizes, int n_in,
                              void* d_out, int out_size, void* d_ws, size_t ws_size,
                              hipStream_t stream) {
    const float* Q   = (const float*)d_in[0];
    const float* K   = (const float*)d_in[1];
    const float* V   = (const float*)d_in[2];
    const float* tmK = (const float*)d_in[3];
    const float* tmV = (const float*)d_in[4];
    const float* am  = (const float*)d_in[5];
    const unsigned char* pm = (const unsigned char*)d_in[6];

    // d_out = [x (B*H*L*D = 262144 floats), attn (B*H*L*L = 2097152 floats)]
    float* x_out    = (float*)d_out;
    float* attn_out = x_out + (size_t)8 * 4 * 256 * 32;

    const int blocks = 8 * 4 * 256;   // one per (b,h,q)
    taspda_fused<<<blocks, 256, 0, stream>>>(Q, K, V, tmK, tmV, am, pm, x_out, attn_out);
}

// Round 2
// 506.045 us; speedup vs baseline: 1.0165x; 1.0165x over previous
//
#include <hip/hip_runtime.h>
#include <math.h>

// TimeAwareScaledDotProductAttention, fused single kernel (round 2).
// B=8, H=4, L=256, D=32, fp32. One block per (b,h,q) row = 8192 blocks x 256.
// Dominant traffic: tmK + tmV = 512 MB streamed once -> HBM-bound.
// Round-2 structure: register-prefetch of V/tmV across the softmax,
// single-barrier softmax, shuffle-based output reduce, nontemporal IO.

typedef float v4f __attribute__((ext_vector_type(4)));

#define LDIM 256
#define DDIM 32
#define NEG_BIG (-4294967295.0f)  // matches -2^32+1 rounded to fp32

__global__ __launch_bounds__(256, 4)
void taspda_fused(const float* __restrict__ Q,
                  const float* __restrict__ K,
                  const float* __restrict__ V,
                  const float* __restrict__ tmK,
                  const float* __restrict__ tmV,
                  const float* __restrict__ attn_mask,
                  const unsigned char* __restrict__ padding_mask,
                  float* __restrict__ x_out,
                  float* __restrict__ attn_out)
{
    const int bid = blockIdx.x;          // (b*H + h)*L + q
    const int q   = bid & (LDIM - 1);
    const int bh  = bid >> 8;
    const int b   = bh >> 2;             // H = 4
    const int t   = threadIdx.x;
    const int kk  = t >> 3;              // k = kk + 32*i
    const int d4  = t & 7;               // float4 index in d
    const int wid = t >> 6;

    __shared__ float els[LDIM];          // energy row, then attn row
    __shared__ float red[8];             // per-wave max (0..3) and sum (4..7)
    __shared__ v4f   xpart[4][8];        // per-wave output partials

    // Q fragment: broadcast within 8-lane groups, L1-served.
    const v4f q4 = *(const v4f*)(Q + (size_t)bid * DDIM + d4 * 4);

    const v4f* tmKrow = (const v4f*)(tmK + (size_t)bid * (LDIM * DDIM));
    const v4f* Krow   = (const v4f*)(K   + (size_t)bh  * (LDIM * DDIM));
    const v4f* tmVrow = (const v4f*)(tmV + (size_t)bid * (LDIM * DDIM));
    const v4f* Vrow   = (const v4f*)(V   + (size_t)bh  * (LDIM * DDIM));

    // ---- phase 1: energy[k] = Q . (K[k] + tmK[q,k]) ----
    // float4 index = t + 256*i: fully coalesced, 1 KiB per wave instruction.
    #pragma unroll
    for (int i = 0; i < 8; ++i) {
        const int k = kk + 32 * i;
        v4f a = __builtin_nontemporal_load(tmKrow + k * 8 + d4); // stream-once
        v4f c = Krow[k * 8 + d4];                                // L2-resident
        float s = q4.x * (a.x + c.x) + q4.y * (a.y + c.y)
                + q4.z * (a.z + c.z) + q4.w * (a.w + c.w);
        s += __shfl_xor(s, 1);
        s += __shfl_xor(s, 2);
        s += __shfl_xor(s, 4);
        if (d4 == 0) els[k] = s;
    }

    // ---- prefetch phase-2 operands; loads stay in flight across softmax ----
    v4f tv[8], vv[8];
    #pragma unroll
    for (int i = 0; i < 8; ++i) {
        const int k = kk + 32 * i;
        tv[i] = __builtin_nontemporal_load(tmVrow + k * 8 + d4);
        vv[i] = Vrow[k * 8 + d4];
    }

    __syncthreads();   // B1: energy row visible

    // ---- softmax over k (thread t owns k = t), single barrier ----
    const float inv_scale = 0.17677669529663687f;   // 1/sqrt(32)
    float e = els[t] * inv_scale + attn_mask[q * LDIM + t];
    if (padding_mask[b * LDIM + t]) e = NEG_BIG;

    float mw = e;                                    // wave max
    #pragma unroll
    for (int o = 32; o >= 1; o >>= 1) mw = fmaxf(mw, __shfl_xor(mw, o));
    const float p = __expf(e - mw);
    float sw = p;                                    // wave sum of exp(e - mw)
    #pragma unroll
    for (int o = 32; o >= 1; o >>= 1) sw += __shfl_xor(sw, o);
    if ((t & 63) == 0) { red[wid] = mw; red[4 + wid] = sw; }
    __syncthreads();   // B2

    const float m = fmaxf(fmaxf(red[0], red[1]), fmaxf(red[2], red[3]));
    const float s = red[4] * __expf(red[0] - m) + red[5] * __expf(red[1] - m)
                  + red[6] * __expf(red[2] - m) + red[7] * __expf(red[3] - m);
    const float attnv = p * __expf(mw - m) / s;

    __builtin_nontemporal_store(attnv, attn_out + (size_t)bid * LDIM + t);
    els[t] = attnv;    // own-slot write; cross-thread reads only after B3
    __syncthreads();   // B3

    // ---- phase 2: x[d] = sum_k attn[k] * (V[k,d] + tmV[q,k,d]) ----
    v4f acc = {0.f, 0.f, 0.f, 0.f};
    #pragma unroll
    for (int i = 0; i < 8; ++i) {
        const int k = kk + 32 * i;
        const float a = els[k];          // LDS broadcast within 8-lane group
        acc += a * (vv[i] + tv[i]);
    }
    // reduce over the 8 kk values held by this wave (lane xor 8,16,32)
    #pragma unroll
    for (int o = 8; o <= 32; o <<= 1) {
        acc.x += __shfl_xor(acc.x, o);
        acc.y += __shfl_xor(acc.y, o);
        acc.z += __shfl_xor(acc.z, o);
        acc.w += __shfl_xor(acc.w, o);
    }
    if ((t & 63) < 8) xpart[wid][d4] = acc;   // lane == d4 for these lanes
    __syncthreads();   // B4
    if (t < 8) {
        v4f r = xpart[0][t] + xpart[1][t] + xpart[2][t] + xpart[3][t];
        __builtin_nontemporal_store(r, (v4f*)(x_out + (size_t)bid * DDIM) + t);
    }
}

extern "C" void kernel_launch(void* const* d_in, const int* in_sizes, int n_in,
                              void* d_out, int out_size, void* d_ws, size_t ws_size,
                              hipStream_t stream) {
    const float* Q   = (const float*)d_in[0];
    const float* K   = (const float*)d_in[1];
    const float* V   = (const float*)d_in[2];
    const float* tmK = (const float*)d_in[3];
    const float* tmV = (const float*)d_in[4];
    const float* am  = (const float*)d_in[5];
    const unsigned char* pm = (const unsigned char*)d_in[6];

    // d_out = [x (8*4*256*32 floats), attn (8*4*256*256 floats)]
    float* x_out    = (float*)d_out;
    float* attn_out = x_out + (size_t)8 * 4 * 256 * 32;

    const int blocks = 8 * 4 * 256;   // one per (b,h,q)
    taspda_fused<<<blocks, 256, 0, stream>>>(Q, K, V, tmK, tmV, am, pm, x_out, attn_out);
}